// Round 13
// baseline (218.298 us; speedup 1.0000x reference)
//
#include <hip/hip_runtime.h>
#include <hip/hip_fp16.h>
#include <math.h>

// GAT layer: N=50000, E=800000, IN=256, H=4, C=32.
// R21: DE-FUSE k_gs into k_scatter + k_gemm (per-stage counter
// visibility lost since R15 — six fused variants all 51-58us, cause
// unattributable). k_scatter rebuilt on a barrier diet: both sides
// counted in ONE pass; 16-barrier Hillis-Steele scan replaced by
// wave-level __shfl_up scan (1 barrier); 256 thr (4 waves/barrier).
// ~44 barriers/block -> 7. LDS bin-sort, R14 fixed-capacity buckets,
// R19 panel-staged GEMM, R13 k_bucket, R14-form k_agg unchanged.

#define NH 4
#define CH 32
#define HC 128
#define IND 256
#define NEG_SLOPE 0.2f
#define CSH 8           // coarse bucket = 256 nodes
#define NCB_MAX 256
#define CHUNK 4096
#define BCAP 6144       // records per coarse bucket (fixed capacity)

typedef __attribute__((ext_vector_type(8))) short bf16x8;
typedef __attribute__((ext_vector_type(16))) float f32x16;

__device__ __forceinline__ unsigned short f2bf(float f) {
    unsigned int u = __float_as_uint(f);
    unsigned int r = (u + 0x7FFFu + ((u >> 16) & 1u)) >> 16;   // RNE
    return (unsigned short)r;
}
__device__ __forceinline__ float bf2f(unsigned short s) {
    return __uint_as_float(((unsigned int)s) << 16);
}

// WT_bf[c][k] = bf16(W[k][c]) — one-time transpose+convert.
// Block 0 zeroes both bucket cursor arrays.
__global__ __launch_bounds__(256) void k_wprep(const float* __restrict__ W,
                                               unsigned short* __restrict__ WT_bf,
                                               int* __restrict__ gcurS,
                                               int* __restrict__ gcurD) {
    int t = blockIdx.x * 256 + threadIdx.x;
    if (blockIdx.x == 0) { gcurS[threadIdx.x] = 0; gcurD[threadIdx.x] = 0; }
    if (t < IND * HC) {
        int c = t >> 8;
        int k = t & 255;
        WT_bf[t] = f2bf(W[k * HC + c]);
    }
}

// Chunked LDS-binned scatter, 256 thr, 16 recs/thread (static-indexed).
// Single count pass for BOTH sides; wave-level shfl scan (1 barrier);
// 7 barriers total per block (was ~44 at 8 waves).
__global__ __launch_bounds__(256) void k_scatter(const int* __restrict__ ei,
                                                 int* __restrict__ gcurS,
                                                 int* __restrict__ gcurD,
                                                 unsigned int* __restrict__ recS,
                                                 unsigned int* __restrict__ recD,
                                                 int E, int NE, int ncb) {
    __shared__ unsigned int srt[CHUNK];                       // 16 KB
    __shared__ int cntS[256], cntD[256];
    __shared__ int offS[256], offD[256];
    __shared__ int curSl[256], curDl[256];
    __shared__ int gposS[256], gposD[256];
    __shared__ int wsumS[4], wsumD[4];

    const int tid  = threadIdx.x;
    const int lane = tid & 63;
    const int wv   = tid >> 6;
    const int t0   = blockIdx.x * CHUNK;
    const int m    = min(CHUNK, NE - t0);

    cntS[tid] = 0; cntD[tid] = 0;

    // load 16 records, static-indexed, validity bitmask
    unsigned int myrec[16];
    unsigned int mval = 0;
#pragma unroll
    for (int j = 0; j < 16; j++) {
        int i = j * 256 + tid;
        int t = t0 + i;
        int src = 0, dst = 0;
        if (i < m) {
            mval |= 1u << j;
            if (t < E) { src = ei[t]; dst = ei[E + t]; }
            else       { src = dst = t - E; }
        }
        myrec[j] = (unsigned int)src | ((unsigned int)dst << 16);
    }
    __syncthreads();                                          // B1: cnt zeroed

    // count BOTH sides in one pass
#pragma unroll
    for (int j = 0; j < 16; j++) {
        if (mval & (1u << j)) {
            unsigned int r = myrec[j];
            atomicAdd(&cntS[(r & 0xFFFFu) >> CSH], 1);
            atomicAdd(&cntD[(r >> 16) >> CSH], 1);
        }
    }
    __syncthreads();                                          // B2: counts done

    // dual wave-level inclusive scan (shfl_up), 1 barrier
    int vS = cntS[tid], vD = cntD[tid];
    int sS = vS, sD = vD;
#pragma unroll
    for (int d = 1; d < 64; d <<= 1) {
        int tS = __shfl_up(sS, d, 64);
        int tD = __shfl_up(sD, d, 64);
        if (lane >= d) { sS += tS; sD += tD; }
    }
    if (lane == 63) { wsumS[wv] = sS; wsumD[wv] = sD; }
    __syncthreads();                                          // B3: wave sums
    int baseS = 0, baseD = 0;
    for (int w = 0; w < wv; w++) { baseS += wsumS[w]; baseD += wsumD[w]; }
    int exS = baseS + sS - vS;
    int exD = baseD + sD - vD;
    offS[tid] = exS; curSl[tid] = exS;
    offD[tid] = exD; curDl[tid] = exD;
    if (tid < ncb) {
        gposS[tid] = vS ? atomicAdd(&gcurS[tid], vS) : 0;
        gposD[tid] = vD ? atomicAdd(&gcurD[tid], vD) : 0;
    }
    __syncthreads();                                          // B4: cur/gpos

    // ---- side S: sort into srt, write out ----
#pragma unroll
    for (int j = 0; j < 16; j++) {
        if (mval & (1u << j)) {
            unsigned int r = myrec[j];
            int p = atomicAdd(&curSl[(r & 0xFFFFu) >> CSH], 1);
            srt[p] = r;
        }
    }
    __syncthreads();                                          // B5: S sorted
    for (int i = tid; i < m; i += 256) {
        unsigned int r = srt[i];
        int cb = (int)(r & 0xFFFFu) >> CSH;
        int p  = gposS[cb] + (i - offS[cb]);
        if (p < BCAP)                                         // safety clamp
            recS[(size_t)cb * BCAP + p] = r;
    }
    __syncthreads();                                          // B6: srt free

    // ---- side D: sort into srt, write out ----
#pragma unroll
    for (int j = 0; j < 16; j++) {
        if (mval & (1u << j)) {
            unsigned int r = myrec[j];
            int p = atomicAdd(&curDl[(r >> 16) >> CSH], 1);
            srt[p] = r;
        }
    }
    __syncthreads();                                          // B7: D sorted
    for (int i = tid; i < m; i += 256) {
        unsigned int r = srt[i];
        int cb = (int)(r >> 16) >> CSH;
        int p  = gposD[cb] + (i - offD[cb]);
        if (p < BCAP)
            recD[(size_t)cb * BCAP + p] = r;
    }
}

// Panel-staged MFMA GEMM, 512 thr, 256 rows/block (R19 form, standalone).
__global__ __launch_bounds__(512) void k_gemm(const float* __restrict__ x,
                                              const unsigned short* __restrict__ WT_bf,
                                              const float* __restrict__ att,
                                              unsigned short* __restrict__ h_bf,
                                              float* __restrict__ al,
                                              float* __restrict__ ar, int N) {
    __shared__ float cs[128 * 132];                    // 67584 B
    unsigned short* xs  = (unsigned short*)cs;         // +0       (34816 B)
    unsigned short* wsP = (unsigned short*)cs + 17408; // byte 34816 (17408 B)

    const int tid  = threadIdx.x;
    const int row0 = blockIdx.x * 256;
    const int wave = tid >> 6;                         // 0..7
    const int lane = tid & 63;
    const int n32  = lane & 31;
    const int half = lane >> 5;

    float4 xv[8];
    int4   wv0, wv1;

#define XLOAD(p)                                                             \
    {                                                                        \
        _Pragma("unroll")                                                    \
        for (int j = 0; j < 8; j++) {                                        \
            int fid = j * 512 + tid;                                         \
            int gr  = row0 + (fid >> 4);                                     \
            float4 t = make_float4(0.f, 0.f, 0.f, 0.f);                      \
            if (gr < N)                                                      \
                t = *(const float4*)(x + (size_t)gr * IND + (p) * 64 +       \
                                     (fid & 15) * 4);                        \
            xv[j] = t;                                                       \
        }                                                                    \
    }
#define WLOAD(p)                                                             \
    {                                                                        \
        const unsigned short* wp = WT_bf + (tid >> 2) * IND + (p) * 64 +     \
                                   (tid & 3) * 16;                           \
        wv0 = *(const int4*)wp;                                              \
        wv1 = *(const int4*)(wp + 8);                                        \
    }
#define XWRITE()                                                             \
    {                                                                        \
        _Pragma("unroll")                                                    \
        for (int j = 0; j < 8; j++) {                                        \
            int fid = j * 512 + tid;                                         \
            int row = fid >> 4;                                              \
            ushort4 o;                                                       \
            o.x = f2bf(xv[j].x); o.y = f2bf(xv[j].y);                        \
            o.z = f2bf(xv[j].z); o.w = f2bf(xv[j].w);                        \
            *(ushort4*)(xs + row * 68 + (fid & 15) * 4) = o;                 \
        }                                                                    \
    }
#define WWRITE()                                                             \
    {                                                                        \
        unsigned short* wq = wsP + (tid >> 2) * 68 + (tid & 3) * 16;         \
        *(int4*)wq       = wv0;                                              \
        *(int4*)(wq + 8) = wv1;                                              \
    }

    XLOAD(0); WLOAD(0);

    f32x16 acc[4];
#pragma unroll
    for (int t = 0; t < 4; t++)
#pragma unroll
        for (int r = 0; r < 16; r++) acc[t][r] = 0.0f;

    const int arow = wave * 32 + n32;
#pragma unroll
    for (int p = 0; p < 4; p++) {
        __syncthreads();               // prior MFMA done reading buffers
        XWRITE(); WWRITE();
        __syncthreads();               // staged data visible
        if (p < 3) { XLOAD(p + 1); WLOAD(p + 1); }  // fly under MFMA below
#pragma unroll
        for (int s = 0; s < 4; s++) {
            bf16x8 a = *(const bf16x8*)(xs + arow * 68 + s * 16 + half * 8);
#pragma unroll
            for (int t = 0; t < 4; t++) {
                bf16x8 b = *(const bf16x8*)(wsP + (t * 32 + n32) * 68 +
                                            s * 16 + half * 8);
                acc[t] = __builtin_amdgcn_mfma_f32_32x32x16_bf16(a, b, acc[t], 0, 0, 0);
            }
        }
    }
#undef XLOAD
#undef WLOAD
#undef XWRITE
#undef WWRITE
    __syncthreads();   // xs/wsP dead; cs epilogue aliases them

    // Two passes: waves 0-3 then 4-7 stage their C tiles through cs.
    for (int pass = 0; pass < 2; pass++) {
        if ((wave >> 2) == pass) {
            const int lw = wave & 3;
#pragma unroll
            for (int t = 0; t < 4; t++)
#pragma unroll
                for (int r = 0; r < 16; r++) {
                    int rl = lw * 32 + (r & 3) + 8 * (r >> 2) + 4 * half;
                    cs[rl * 132 + t * 33 + n32] = acc[t][r];
                }
        }
        __syncthreads();

        const int rl   = tid >> 2;
        const int hq   = tid & 3;
        const int orow = row0 + pass * 128 + rl;
        if (orow < N) {
            const float* cr = cs + rl * 132 + hq * 33;
            unsigned short* hp = h_bf + (size_t)orow * HC + hq * CH;
#pragma unroll
            for (int c = 0; c < 32; c += 8) {
                ushort4 o0, o1;
                o0.x = f2bf(cr[c]);     o0.y = f2bf(cr[c + 1]);
                o0.z = f2bf(cr[c + 2]); o0.w = f2bf(cr[c + 3]);
                o1.x = f2bf(cr[c + 4]); o1.y = f2bf(cr[c + 5]);
                o1.z = f2bf(cr[c + 6]); o1.w = f2bf(cr[c + 7]);
                *(ushort4*)(hp + c) = o0;
                *(ushort4*)(hp + c + 4) = o1;
            }
            const float* w0 = att + hq * (2 * CH);
            float sl = 0.f, sr = 0.f;
#pragma unroll
            for (int c = 0; c < CH; c++) {
                float v2 = cr[c];
                sl += v2 * w0[c];
                sr += v2 * w0[CH + c];
            }
            al[orow * NH + hq] = sl;
            ar[orow * NH + hq] = sr;
        }
        __syncthreads();
    }
}

// Fused bucket kernel, 2*ncb blocks:
//   blocks [0,ncb):     D-side rebin -> node-level CSR (adjD + rowB/rowE)
//   blocks [ncb,2*ncb): S-side LDS-binned denominator -> arw={ar,1/sum}
__global__ __launch_bounds__(256) void k_bucket(const unsigned int* __restrict__ recS,
                                                const unsigned int* __restrict__ recD,
                                                const int* __restrict__ gcurS,
                                                const int* __restrict__ gcurD,
                                                const float* __restrict__ al,
                                                const float* __restrict__ ar,
                                                unsigned short* __restrict__ adjD,
                                                int* __restrict__ rowB,
                                                int* __restrict__ rowE,
                                                float* __restrict__ arw,
                                                int ncb, int N) {
    __shared__ int cnt[256], cur[256], sc[256];   // 3 KB (rebin side)
    __shared__ float lsums[256 * NH];             // 4 KB (denom side)
    __shared__ float lar[256 * NH];               // 4 KB (denom side)
    const int tid = threadIdx.x;

    if (blockIdx.x < ncb) {
        // ---- D-side rebin ----
        const int cb = blockIdx.x;
        const int b0 = cb * BCAP;
        const int tot_rec = min(gcurD[cb], BCAP);

        cnt[tid] = 0;
        __syncthreads();
        for (int i = tid; i < tot_rec; i += 256) {
            unsigned int r = recD[b0 + i];
            atomicAdd(&cnt[(r >> 16) & 255], 1);
        }
        __syncthreads();
        int v = cnt[tid];
        sc[tid] = v;
        __syncthreads();
        for (int o = 1; o < 256; o <<= 1) {
            int t = (tid >= o) ? sc[tid - o] : 0;
            __syncthreads();
            sc[tid] += t;
            __syncthreads();
        }
        int ex = sc[tid] - v;
        int node_g = (cb << CSH) + tid;
        if (node_g < N) { rowB[node_g] = b0 + ex; rowE[node_g] = b0 + ex + v; }
        cur[tid] = ex;
        __syncthreads();
        for (int i = tid; i < tot_rec; i += 256) {
            unsigned int r = recD[b0 + i];
            int node = (int)(r >> 16) & 255;
            int p = atomicAdd(&cur[node], 1);
            adjD[b0 + p] = (unsigned short)(r & 0xFFFFu);
        }
    } else {
        // ---- S-side denominator + arw pack ----
        const int cb = blockIdx.x - ncb;
        const int b0 = cb * BCAP;
        const int b1 = b0 + min(gcurS[cb], BCAP);
        const int node_g = (cb << CSH) + tid;

        float4 arv = make_float4(0.f, 0.f, 0.f, 0.f);
        if (node_g < N) arv = *(const float4*)(ar + (size_t)node_g * NH);
        *(float4*)(lar + tid * NH) = arv;
        *(float4*)(lsums + tid * NH) = make_float4(0.f, 0.f, 0.f, 0.f);
        __syncthreads();

        int i = b0 + tid;
        for (; i + 256 < b1; i += 512) {
            unsigned int r0 = recS[i];
            unsigned int r1 = recS[i + 256];
            int sl0 = (int)(r0 & 255u), dst0 = (int)(r0 >> 16);
            int sl1 = (int)(r1 & 255u), dst1 = (int)(r1 >> 16);
            float4 av0 = *(const float4*)(al + (size_t)dst0 * NH);
            float4 av1 = *(const float4*)(al + (size_t)dst1 * NH);
            const float* w0 = lar + sl0 * NH;
            const float* w1 = lar + sl1 * NH;
            float a0 = av0.x + w0[0], a1 = av0.y + w0[1];
            float a2 = av0.z + w0[2], a3 = av0.w + w0[3];
            float c0 = av1.x + w1[0], c1 = av1.y + w1[1];
            float c2 = av1.z + w1[2], c3 = av1.w + w1[3];
            a0 = (a0 > 0.f) ? a0 : NEG_SLOPE * a0;
            a1 = (a1 > 0.f) ? a1 : NEG_SLOPE * a1;
            a2 = (a2 > 0.f) ? a2 : NEG_SLOPE * a2;
            a3 = (a3 > 0.f) ? a3 : NEG_SLOPE * a3;
            c0 = (c0 > 0.f) ? c0 : NEG_SLOPE * c0;
            c1 = (c1 > 0.f) ? c1 : NEG_SLOPE * c1;
            c2 = (c2 > 0.f) ? c2 : NEG_SLOPE * c2;
            c3 = (c3 > 0.f) ? c3 : NEG_SLOPE * c3;
            float* s0 = lsums + sl0 * NH;
            float* s1 = lsums + sl1 * NH;
            atomicAdd(s0 + 0, __expf(a0));
            atomicAdd(s0 + 1, __expf(a1));
            atomicAdd(s0 + 2, __expf(a2));
            atomicAdd(s0 + 3, __expf(a3));
            atomicAdd(s1 + 0, __expf(c0));
            atomicAdd(s1 + 1, __expf(c1));
            atomicAdd(s1 + 2, __expf(c2));
            atomicAdd(s1 + 3, __expf(c3));
        }
        if (i < b1) {
            unsigned int r = recS[i];
            int slot = (int)(r & 255u);
            int dst  = (int)(r >> 16);
            float4 alv = *(const float4*)(al + (size_t)dst * NH);
            const float* av = lar + slot * NH;
            float a0 = alv.x + av[0], a1 = alv.y + av[1];
            float a2 = alv.z + av[2], a3 = alv.w + av[3];
            a0 = (a0 > 0.f) ? a0 : NEG_SLOPE * a0;
            a1 = (a1 > 0.f) ? a1 : NEG_SLOPE * a1;
            a2 = (a2 > 0.f) ? a2 : NEG_SLOPE * a2;
            a3 = (a3 > 0.f) ? a3 : NEG_SLOPE * a3;
            float* sp = lsums + slot * NH;
            atomicAdd(sp + 0, __expf(a0));
            atomicAdd(sp + 1, __expf(a1));
            atomicAdd(sp + 2, __expf(a2));
            atomicAdd(sp + 3, __expf(a3));
        }
        __syncthreads();

        if (node_g < N) {
            const float* sp = lsums + tid * NH;
            float4 p0 = make_float4(arv.x, 1.0f / (sp[0] + 1e-16f),
                                    arv.y, 1.0f / (sp[1] + 1e-16f));
            float4 p1 = make_float4(arv.z, 1.0f / (sp[2] + 1e-16f),
                                    arv.w, 1.0f / (sp[3] + 1e-16f));
            *(float4*)(arw + (size_t)node_g * 8)     = p0;
            *(float4*)(arw + (size_t)node_g * 8 + 4) = p1;
        }
    }
}

// Fused weight+aggregate (R14 form — measured 41.7us floor).
__global__ __launch_bounds__(256) void k_agg(const int* __restrict__ rowB,
                                             const int* __restrict__ rowE,
                                             const unsigned short* __restrict__ adjD,
                                             const float* __restrict__ al,
                                             const float* __restrict__ arw,
                                             const unsigned short* __restrict__ h_bf,
                                             const float* __restrict__ bias,
                                             float* __restrict__ out, int N) {
    const int g = threadIdx.x >> 5;
    const int n = blockIdx.x * 8 + g;
    if (n >= N) return;
    const int l  = threadIdx.x & 31;
    const int c0 = l * 4;            // 4 contiguous channels
    const int hh = l >> 3;           // head of this lane's channels
    const int beg = rowB[n], end = rowE[n];
    const float alv = al[n * NH + hh];

    float a0 = 0.f, a1 = 0.f, a2 = 0.f, a3 = 0.f;

    for (int base = beg; base < end; base += 32) {
        int idx = base + l;
        int av  = (idx < end) ? (int)adjD[idx] : 0;   // coop preload (64B/group)
        int cnt = min(32, end - base);
        int e = 0;
        for (; e + 4 <= cnt; e += 4) {
            int s0 = __shfl(av, e,     32);
            int s1 = __shfl(av, e + 1, 32);
            int s2 = __shfl(av, e + 2, 32);
            int s3 = __shfl(av, e + 3, 32);
            ushort4 u0 = *(const ushort4*)(h_bf + (size_t)s0 * HC + c0);
            ushort4 u1 = *(const ushort4*)(h_bf + (size_t)s1 * HC + c0);
            ushort4 u2 = *(const ushort4*)(h_bf + (size_t)s2 * HC + c0);
            ushort4 u3 = *(const ushort4*)(h_bf + (size_t)s3 * HC + c0);
            float2 p0 = *(const float2*)(arw + (size_t)s0 * 8 + hh * 2);
            float2 p1 = *(const float2*)(arw + (size_t)s1 * 8 + hh * 2);
            float2 p2 = *(const float2*)(arw + (size_t)s2 * 8 + hh * 2);
            float2 p3 = *(const float2*)(arw + (size_t)s3 * 8 + hh * 2);
            float t0 = alv + p0.x; t0 = (t0 > 0.f) ? t0 : NEG_SLOPE * t0;
            float t1 = alv + p1.x; t1 = (t1 > 0.f) ? t1 : NEG_SLOPE * t1;
            float t2 = alv + p2.x; t2 = (t2 > 0.f) ? t2 : NEG_SLOPE * t2;
            float t3 = alv + p3.x; t3 = (t3 > 0.f) ? t3 : NEG_SLOPE * t3;
            float w0 = __expf(t0) * p0.y;
            float w1 = __expf(t1) * p1.y;
            float w2 = __expf(t2) * p2.y;
            float w3 = __expf(t3) * p3.y;
            a0 += bf2f(u0.x) * w0; a1 += bf2f(u0.y) * w0;
            a2 += bf2f(u0.z) * w0; a3 += bf2f(u0.w) * w0;
            a0 += bf2f(u1.x) * w1; a1 += bf2f(u1.y) * w1;
            a2 += bf2f(u1.z) * w1; a3 += bf2f(u1.w) * w1;
            a0 += bf2f(u2.x) * w2; a1 += bf2f(u2.y) * w2;
            a2 += bf2f(u2.z) * w2; a3 += bf2f(u2.w) * w2;
            a0 += bf2f(u3.x) * w3; a1 += bf2f(u3.y) * w3;
            a2 += bf2f(u3.z) * w3; a3 += bf2f(u3.w) * w3;
        }
        for (; e < cnt; e++) {
            int s0 = __shfl(av, e, 32);
            ushort4 u0 = *(const ushort4*)(h_bf + (size_t)s0 * HC + c0);
            float2 p0 = *(const float2*)(arw + (size_t)s0 * 8 + hh * 2);
            float t0 = alv + p0.x; t0 = (t0 > 0.f) ? t0 : NEG_SLOPE * t0;
            float w0 = __expf(t0) * p0.y;
            a0 += bf2f(u0.x) * w0; a1 += bf2f(u0.y) * w0;
            a2 += bf2f(u0.z) * w0; a3 += bf2f(u0.w) * w0;
        }
    }
    float4 b4 = *(const float4*)(bias + c0);
    *(float4*)(out + (size_t)n * HC + c0) =
        make_float4(a0 + b4.x, a1 + b4.y, a2 + b4.z, a3 + b4.w);
}

extern "C" void kernel_launch(void* const* d_in, const int* in_sizes, int n_in,
                              void* d_out, int out_size, void* d_ws, size_t ws_size,
                              hipStream_t stream) {
    const float* x    = (const float*)d_in[0];
    const float* W    = (const float*)d_in[1];
    const float* att  = (const float*)d_in[2];
    const float* bias = (const float*)d_in[3];
    const int*   ei   = (const int*)d_in[4];

    const int N  = in_sizes[0] / IND;     // 50000
    const int E  = in_sizes[4] / 2;       // 800000
    const int NE = E + N;
    const int ncb = (N + (1 << CSH) - 1) >> CSH;   // 196
    const int nsb = (NE + CHUNK - 1) / CHUNK;      // 208 scatter blocks
    const int ngb = (N + 255) / 256;               // 196 gemm blocks (512 thr)
    float* out = (float*)d_out;
    const int nodeTot = N * NH;
    const size_t capTot = (size_t)ncb * BCAP;      // 196*6144 ≈ 1.2M recs/side

    // ws layout
    unsigned short* h_bf  = (unsigned short*)d_ws;             // N*128 u16 = 12.8MB
    unsigned short* WT_bf = h_bf + (size_t)N * HC;             // 32K u16
    float* al   = (float*)(WT_bf + IND * HC);                  // N*4 f32
    float* ar   = al + nodeTot;                                // N*4
    float* arw  = ar + nodeTot;                                // N*8 = 1.6MB
    unsigned int* recS = (unsigned int*)(arw + (size_t)N * 8); // ncb*BCAP u32
    unsigned int* recD = recS + capTot;                        // ncb*BCAP u32
    unsigned short* adjD = (unsigned short*)(recD + capTot);   // ncb*BCAP u16
    int* rowB    = (int*)(adjD + capTot + (capTot & 1));       // N
    int* rowE    = rowB + N;                                   // N
    int* gcurS   = rowE + N;                                   // ncb
    int* gcurD   = gcurS + NCB_MAX;                            // ncb

    k_wprep<<<(IND * HC + 255) / 256, 256, 0, stream>>>(W, WT_bf, gcurS, gcurD);
    k_scatter<<<nsb, 256, 0, stream>>>(ei, gcurS, gcurD, recS, recD, E, NE, ncb);
    k_gemm<<<ngb, 512, 0, stream>>>(x, WT_bf, att, h_bf, al, ar, N);
    k_bucket<<<2 * ncb, 256, 0, stream>>>(recS, recD, gcurS, gcurD, al, ar,
                                          adjD, rowB, rowE, arw, ncb, N);
    k_agg<<<(N + 7) / 8, 256, 0, stream>>>(rowB, rowE, adjD, al, arw, h_bf,
                                           bias, out, N);
}

// Round 15
// 197.568 us; speedup vs baseline: 1.1049x; 1.1049x over previous
//
#include <hip/hip_runtime.h>
#include <hip/hip_fp16.h>
#include <math.h>

// GAT layer: N=50000, E=800000, IN=256, H=4, C=32.
// R22 (resubmit; R14-round bench was a GPUAcquisitionTimeout — never
// ran). GEMM reverted to the R9/R14 barrier-free form (256 thr, 128
// rows/block, 391 blocks, direct x loads, NO barriers in the K-loop ->
// compiler pipelines loads across iterations; measured <=41us vs the
// panel-staged rewrite's 44 — R18/R19's per-panel barriers broke the
// compiler's pipelining). Lean R21 scatter (7 barriers, static-indexed)
// fused in front (blocks [0,nsb)), aliasing the gemm's 66KB cs.
// R14 fixed-capacity buckets, R13 k_bucket, R14-form k_agg unchanged.
// Note: harness's 256MB workspace zero-fill (~42us) is in the timed
// stream and immovable.

#define NH 4
#define CH 32
#define HC 128
#define IND 256
#define NEG_SLOPE 0.2f
#define CSH 8           // coarse bucket = 256 nodes
#define NCB_MAX 256
#define CHUNK 4096
#define BCAP 6144       // records per coarse bucket (fixed capacity)

typedef __attribute__((ext_vector_type(8))) short bf16x8;
typedef __attribute__((ext_vector_type(16))) float f32x16;

__device__ __forceinline__ unsigned short f2bf(float f) {
    unsigned int u = __float_as_uint(f);
    unsigned int r = (u + 0x7FFFu + ((u >> 16) & 1u)) >> 16;   // RNE
    return (unsigned short)r;
}
__device__ __forceinline__ float bf2f(unsigned short s) {
    return __uint_as_float(((unsigned int)s) << 16);
}

// WT_bf[c][k] = bf16(W[k][c]) — one-time transpose+convert.
// Block 0 zeroes both bucket cursor arrays.
__global__ __launch_bounds__(256) void k_wprep(const float* __restrict__ W,
                                               unsigned short* __restrict__ WT_bf,
                                               int* __restrict__ gcurS,
                                               int* __restrict__ gcurD) {
    int t = blockIdx.x * 256 + threadIdx.x;
    if (blockIdx.x == 0) { gcurS[threadIdx.x] = 0; gcurD[threadIdx.x] = 0; }
    if (t < IND * HC) {
        int c = t >> 8;
        int k = t & 255;
        WT_bf[t] = f2bf(W[k * HC + c]);
    }
}

// Fused scatter + GEMM, 256 threads/block.
// Blocks [0,nsb): lean LDS-binned scatter (R21 form: one count pass for
// both sides, shfl_up scan, 7 barriers). Blocks [nsb,nsb+ngb): R9-form
// barrier-free-K MFMA GEMM over 128 rows.
__global__ __launch_bounds__(256) void k_gs(const float* __restrict__ x,
                                            const unsigned short* __restrict__ WT_bf,
                                            const float* __restrict__ att,
                                            unsigned short* __restrict__ h_bf,
                                            float* __restrict__ al,
                                            float* __restrict__ ar,
                                            const int* __restrict__ ei,
                                            int* __restrict__ gcurS,
                                            int* __restrict__ gcurD,
                                            unsigned int* __restrict__ recS,
                                            unsigned int* __restrict__ recD,
                                            int E, int NE, int ncb, int nsb, int N) {
    __shared__ float cs[128 * 129];                    // 66048 B (both paths)

    const int tid = threadIdx.x;

    if (blockIdx.x < nsb) {
        // ============ scatter path (256 thr, R21 lean form) ============
        unsigned int* srt = (unsigned int*)cs;                 // 16 KB
        int* cntS  = (int*)(srt + CHUNK);
        int* cntD  = cntS + 256;
        int* offS  = cntD + 256;
        int* offD  = offS + 256;
        int* curSl = offD + 256;
        int* curDl = curSl + 256;
        int* gposS = curDl + 256;
        int* gposD = gposS + 256;
        int* wsumS = gposD + 256;
        int* wsumD = wsumS + 4;

        const int lane = tid & 63;
        const int wv   = tid >> 6;
        const int t0   = blockIdx.x * CHUNK;
        const int m    = min(CHUNK, NE - t0);

        cntS[tid] = 0; cntD[tid] = 0;

        unsigned int myrec[16];
        unsigned int mval = 0;
#pragma unroll
        for (int j = 0; j < 16; j++) {
            int i = j * 256 + tid;
            int t = t0 + i;
            int src = 0, dst = 0;
            if (i < m) {
                mval |= 1u << j;
                if (t < E) { src = ei[t]; dst = ei[E + t]; }
                else       { src = dst = t - E; }
            }
            myrec[j] = (unsigned int)src | ((unsigned int)dst << 16);
        }
        __syncthreads();                                      // B1

#pragma unroll
        for (int j = 0; j < 16; j++) {
            if (mval & (1u << j)) {
                unsigned int r = myrec[j];
                atomicAdd(&cntS[(r & 0xFFFFu) >> CSH], 1);
                atomicAdd(&cntD[(r >> 16) >> CSH], 1);
            }
        }
        __syncthreads();                                      // B2

        int vS = cntS[tid], vD = cntD[tid];
        int sS = vS, sD = vD;
#pragma unroll
        for (int d = 1; d < 64; d <<= 1) {
            int tS = __shfl_up(sS, d, 64);
            int tD = __shfl_up(sD, d, 64);
            if (lane >= d) { sS += tS; sD += tD; }
        }
        if (lane == 63) { wsumS[wv] = sS; wsumD[wv] = sD; }
        __syncthreads();                                      // B3
        int baseS = 0, baseD = 0;
        for (int w = 0; w < wv; w++) { baseS += wsumS[w]; baseD += wsumD[w]; }
        int exS = baseS + sS - vS;
        int exD = baseD + sD - vD;
        offS[tid] = exS; curSl[tid] = exS;
        offD[tid] = exD; curDl[tid] = exD;
        if (tid < ncb) {
            gposS[tid] = vS ? atomicAdd(&gcurS[tid], vS) : 0;
            gposD[tid] = vD ? atomicAdd(&gcurD[tid], vD) : 0;
        }
        __syncthreads();                                      // B4

#pragma unroll
        for (int j = 0; j < 16; j++) {
            if (mval & (1u << j)) {
                unsigned int r = myrec[j];
                int p = atomicAdd(&curSl[(r & 0xFFFFu) >> CSH], 1);
                srt[p] = r;
            }
        }
        __syncthreads();                                      // B5
        for (int i = tid; i < m; i += 256) {
            unsigned int r = srt[i];
            int cb = (int)(r & 0xFFFFu) >> CSH;
            int p  = gposS[cb] + (i - offS[cb]);
            if (p < BCAP)
                recS[(size_t)cb * BCAP + p] = r;
        }
        __syncthreads();                                      // B6

#pragma unroll
        for (int j = 0; j < 16; j++) {
            if (mval & (1u << j)) {
                unsigned int r = myrec[j];
                int p = atomicAdd(&curDl[(r >> 16) >> CSH], 1);
                srt[p] = r;
            }
        }
        __syncthreads();                                      // B7
        for (int i = tid; i < m; i += 256) {
            unsigned int r = srt[i];
            int cb = (int)(r >> 16) >> CSH;
            int p  = gposD[cb] + (i - offD[cb]);
            if (p < BCAP)
                recD[(size_t)cb * BCAP + p] = r;
        }
        return;
    }

    // ========== GEMM path (256 thr, 128 rows, R9 barrier-free) ==========
    unsigned short* wsT = (unsigned short*)cs;         // [128][258] = 66048 B

    const int row0 = (blockIdx.x - nsb) * 128;
    const int wave = tid >> 6;
    const int lane = tid & 63;
    const int n32  = lane & 31;
    const int half = lane >> 5;

    // stage full W once: thread copies half a column (128 shorts, int4 x16)
    {
        int c  = tid >> 1;
        int kh = (tid & 1) * 128;
        const unsigned short* src = WT_bf + c * IND + kh;
        unsigned short* dst = wsT + c * 258 + kh;
#pragma unroll
        for (int j = 0; j < 128; j += 8)
            *(int4*)(dst + j) = *(const int4*)(src + j);
    }
    __syncthreads();

    const int row   = row0 + wave * 32 + n32;
    const bool valid = row < N;
    const float* xrow = x + (size_t)row * IND + half * 8;

    f32x16 acc[4];
#pragma unroll
    for (int t = 0; t < 4; t++)
#pragma unroll
        for (int r = 0; r < 16; r++) acc[t][r] = 0.0f;

    // 16 K-steps of 16; NO barriers inside.
#pragma unroll 4
    for (int s = 0; s < 16; s++) {
        float4 v0 = make_float4(0.f, 0.f, 0.f, 0.f);
        float4 v1 = v0;
        if (valid) {
            v0 = *(const float4*)(xrow + s * 16);
            v1 = *(const float4*)(xrow + s * 16 + 4);
        }
        bf16x8 a;
        a[0] = (short)f2bf(v0.x); a[1] = (short)f2bf(v0.y);
        a[2] = (short)f2bf(v0.z); a[3] = (short)f2bf(v0.w);
        a[4] = (short)f2bf(v1.x); a[5] = (short)f2bf(v1.y);
        a[6] = (short)f2bf(v1.z); a[7] = (short)f2bf(v1.w);
#pragma unroll
        for (int t = 0; t < 4; t++) {
            bf16x8 b = *(const bf16x8*)(wsT + (t * 32 + n32) * 258 + s * 16 + half * 8);
            acc[t] = __builtin_amdgcn_mfma_f32_32x32x16_bf16(a, b, acc[t], 0, 0, 0);
        }
    }
    __syncthreads();   // wsT dead; cs aliases it

    // C frags -> cs (129-f32 stride: banks = rl + col, 2-way max = free)
#pragma unroll
    for (int t = 0; t < 4; t++)
#pragma unroll
        for (int r = 0; r < 16; r++) {
            int rl = wave * 32 + (r & 3) + 8 * (r >> 2) + 4 * half;
            cs[rl * 129 + t * 32 + n32] = acc[t][r];
        }
    __syncthreads();

    // epilogue: thread -> (row_local = tid>>1, col-half = tid&1 -> heads 2h,2h+1)
    const int rl   = tid >> 1;
    const int chf  = tid & 1;
    const int orow = row0 + rl;
    if (orow < N) {
        const float* cr = cs + rl * 129 + chf * 64;
        unsigned short* hp = h_bf + (size_t)orow * HC + chf * 64;
#pragma unroll
        for (int c = 0; c < 64; c += 8) {
            ushort4 o0, o1;
            o0.x = f2bf(cr[c]);     o0.y = f2bf(cr[c + 1]);
            o0.z = f2bf(cr[c + 2]); o0.w = f2bf(cr[c + 3]);
            o1.x = f2bf(cr[c + 4]); o1.y = f2bf(cr[c + 5]);
            o1.z = f2bf(cr[c + 6]); o1.w = f2bf(cr[c + 7]);
            *(ushort4*)(hp + c) = o0;
            *(ushort4*)(hp + c + 4) = o1;
        }
        const int h0 = 2 * chf, h1 = 2 * chf + 1;
        const float* w0 = att + h0 * (2 * CH);
        const float* w1 = att + h1 * (2 * CH);
        float sl0 = 0.f, sr0 = 0.f, sl1 = 0.f, sr1 = 0.f;
#pragma unroll
        for (int c = 0; c < CH; c++) {
            float v0 = cr[c];
            float v1 = cr[CH + c];
            sl0 += v0 * w0[c];  sr0 += v0 * w0[CH + c];
            sl1 += v1 * w1[c];  sr1 += v1 * w1[CH + c];
        }
        al[orow * NH + h0] = sl0;  al[orow * NH + h1] = sl1;
        ar[orow * NH + h0] = sr0;  ar[orow * NH + h1] = sr1;
    }
}

// Fused bucket kernel, 2*ncb blocks:
//   blocks [0,ncb):     D-side rebin -> node-level CSR (adjD + rowB/rowE)
//   blocks [ncb,2*ncb): S-side LDS-binned denominator -> arw={ar,1/sum}
__global__ __launch_bounds__(256) void k_bucket(const unsigned int* __restrict__ recS,
                                                const unsigned int* __restrict__ recD,
                                                const int* __restrict__ gcurS,
                                                const int* __restrict__ gcurD,
                                                const float* __restrict__ al,
                                                const float* __restrict__ ar,
                                                unsigned short* __restrict__ adjD,
                                                int* __restrict__ rowB,
                                                int* __restrict__ rowE,
                                                float* __restrict__ arw,
                                                int ncb, int N) {
    __shared__ int cnt[256], cur[256], sc[256];   // 3 KB (rebin side)
    __shared__ float lsums[256 * NH];             // 4 KB (denom side)
    __shared__ float lar[256 * NH];               // 4 KB (denom side)
    const int tid = threadIdx.x;

    if (blockIdx.x < ncb) {
        // ---- D-side rebin ----
        const int cb = blockIdx.x;
        const int b0 = cb * BCAP;
        const int tot_rec = min(gcurD[cb], BCAP);

        cnt[tid] = 0;
        __syncthreads();
        for (int i = tid; i < tot_rec; i += 256) {
            unsigned int r = recD[b0 + i];
            atomicAdd(&cnt[(r >> 16) & 255], 1);
        }
        __syncthreads();
        int v = cnt[tid];
        sc[tid] = v;
        __syncthreads();
        for (int o = 1; o < 256; o <<= 1) {
            int t = (tid >= o) ? sc[tid - o] : 0;
            __syncthreads();
            sc[tid] += t;
            __syncthreads();
        }
        int ex = sc[tid] - v;
        int node_g = (cb << CSH) + tid;
        if (node_g < N) { rowB[node_g] = b0 + ex; rowE[node_g] = b0 + ex + v; }
        cur[tid] = ex;
        __syncthreads();
        for (int i = tid; i < tot_rec; i += 256) {
            unsigned int r = recD[b0 + i];
            int node = (int)(r >> 16) & 255;
            int p = atomicAdd(&cur[node], 1);
            adjD[b0 + p] = (unsigned short)(r & 0xFFFFu);
        }
    } else {
        // ---- S-side denominator + arw pack ----
        const int cb = blockIdx.x - ncb;
        const int b0 = cb * BCAP;
        const int b1 = b0 + min(gcurS[cb], BCAP);
        const int node_g = (cb << CSH) + tid;

        float4 arv = make_float4(0.f, 0.f, 0.f, 0.f);
        if (node_g < N) arv = *(const float4*)(ar + (size_t)node_g * NH);
        *(float4*)(lar + tid * NH) = arv;
        *(float4*)(lsums + tid * NH) = make_float4(0.f, 0.f, 0.f, 0.f);
        __syncthreads();

        int i = b0 + tid;
        for (; i + 256 < b1; i += 512) {
            unsigned int r0 = recS[i];
            unsigned int r1 = recS[i + 256];
            int sl0 = (int)(r0 & 255u), dst0 = (int)(r0 >> 16);
            int sl1 = (int)(r1 & 255u), dst1 = (int)(r1 >> 16);
            float4 av0 = *(const float4*)(al + (size_t)dst0 * NH);
            float4 av1 = *(const float4*)(al + (size_t)dst1 * NH);
            const float* w0 = lar + sl0 * NH;
            const float* w1 = lar + sl1 * NH;
            float a0 = av0.x + w0[0], a1 = av0.y + w0[1];
            float a2 = av0.z + w0[2], a3 = av0.w + w0[3];
            float c0 = av1.x + w1[0], c1 = av1.y + w1[1];
            float c2 = av1.z + w1[2], c3 = av1.w + w1[3];
            a0 = (a0 > 0.f) ? a0 : NEG_SLOPE * a0;
            a1 = (a1 > 0.f) ? a1 : NEG_SLOPE * a1;
            a2 = (a2 > 0.f) ? a2 : NEG_SLOPE * a2;
            a3 = (a3 > 0.f) ? a3 : NEG_SLOPE * a3;
            c0 = (c0 > 0.f) ? c0 : NEG_SLOPE * c0;
            c1 = (c1 > 0.f) ? c1 : NEG_SLOPE * c1;
            c2 = (c2 > 0.f) ? c2 : NEG_SLOPE * c2;
            c3 = (c3 > 0.f) ? c3 : NEG_SLOPE * c3;
            float* s0 = lsums + sl0 * NH;
            float* s1 = lsums + sl1 * NH;
            atomicAdd(s0 + 0, __expf(a0));
            atomicAdd(s0 + 1, __expf(a1));
            atomicAdd(s0 + 2, __expf(a2));
            atomicAdd(s0 + 3, __expf(a3));
            atomicAdd(s1 + 0, __expf(c0));
            atomicAdd(s1 + 1, __expf(c1));
            atomicAdd(s1 + 2, __expf(c2));
            atomicAdd(s1 + 3, __expf(c3));
        }
        if (i < b1) {
            unsigned int r = recS[i];
            int slot = (int)(r & 255u);
            int dst  = (int)(r >> 16);
            float4 alv = *(const float4*)(al + (size_t)dst * NH);
            const float* av = lar + slot * NH;
            float a0 = alv.x + av[0], a1 = alv.y + av[1];
            float a2 = alv.z + av[2], a3 = alv.w + av[3];
            a0 = (a0 > 0.f) ? a0 : NEG_SLOPE * a0;
            a1 = (a1 > 0.f) ? a1 : NEG_SLOPE * a1;
            a2 = (a2 > 0.f) ? a2 : NEG_SLOPE * a2;
            a3 = (a3 > 0.f) ? a3 : NEG_SLOPE * a3;
            float* sp = lsums + slot * NH;
            atomicAdd(sp + 0, __expf(a0));
            atomicAdd(sp + 1, __expf(a1));
            atomicAdd(sp + 2, __expf(a2));
            atomicAdd(sp + 3, __expf(a3));
        }
        __syncthreads();

        if (node_g < N) {
            const float* sp = lsums + tid * NH;
            float4 p0 = make_float4(arv.x, 1.0f / (sp[0] + 1e-16f),
                                    arv.y, 1.0f / (sp[1] + 1e-16f));
            float4 p1 = make_float4(arv.z, 1.0f / (sp[2] + 1e-16f),
                                    arv.w, 1.0f / (sp[3] + 1e-16f));
            *(float4*)(arw + (size_t)node_g * 8)     = p0;
            *(float4*)(arw + (size_t)node_g * 8 + 4) = p1;
        }
    }
}

// Fused weight+aggregate (R14 form — measured 41.7us floor).
__global__ __launch_bounds__(256) void k_agg(const int* __restrict__ rowB,
                                             const int* __restrict__ rowE,
                                             const unsigned short* __restrict__ adjD,
                                             const float* __restrict__ al,
                                             const float* __restrict__ arw,
                                             const unsigned short* __restrict__ h_bf,
                                             const float* __restrict__ bias,
                                             float* __restrict__ out, int N) {
    const int g = threadIdx.x >> 5;
    const int n = blockIdx.x * 8 + g;
    if (n >= N) return;
    const int l  = threadIdx.x & 31;
    const int c0 = l * 4;            // 4 contiguous channels
    const int hh = l >> 3;           // head of this lane's channels
    const int beg = rowB[n], end = rowE[n];
    const float alv = al[n * NH + hh];

    float a0 = 0.f, a1 = 0.f, a2 = 0.f, a3 = 0.f;

    for (int base = beg; base < end; base += 32) {
        int idx = base + l;
        int av  = (idx < end) ? (int)adjD[idx] : 0;   // coop preload (64B/group)
        int cnt = min(32, end - base);
        int e = 0;
        for (; e + 4 <= cnt; e += 4) {
            int s0 = __shfl(av, e,     32);
            int s1 = __shfl(av, e + 1, 32);
            int s2 = __shfl(av, e + 2, 32);
            int s3 = __shfl(av, e + 3, 32);
            ushort4 u0 = *(const ushort4*)(h_bf + (size_t)s0 * HC + c0);
            ushort4 u1 = *(const ushort4*)(h_bf + (size_t)s1 * HC + c0);
            ushort4 u2 = *(const ushort4*)(h_bf + (size_t)s2 * HC + c0);
            ushort4 u3 = *(const ushort4*)(h_bf + (size_t)s3 * HC + c0);
            float2 p0 = *(const float2*)(arw + (size_t)s0 * 8 + hh * 2);
            float2 p1 = *(const float2*)(arw + (size_t)s1 * 8 + hh * 2);
            float2 p2 = *(const float2*)(arw + (size_t)s2 * 8 + hh * 2);
            float2 p3 = *(const float2*)(arw + (size_t)s3 * 8 + hh * 2);
            float t0 = alv + p0.x; t0 = (t0 > 0.f) ? t0 : NEG_SLOPE * t0;
            float t1 = alv + p1.x; t1 = (t1 > 0.f) ? t1 : NEG_SLOPE * t1;
            float t2 = alv + p2.x; t2 = (t2 > 0.f) ? t2 : NEG_SLOPE * t2;
            float t3 = alv + p3.x; t3 = (t3 > 0.f) ? t3 : NEG_SLOPE * t3;
            float w0 = __expf(t0) * p0.y;
            float w1 = __expf(t1) * p1.y;
            float w2 = __expf(t2) * p2.y;
            float w3 = __expf(t3) * p3.y;
            a0 += bf2f(u0.x) * w0; a1 += bf2f(u0.y) * w0;
            a2 += bf2f(u0.z) * w0; a3 += bf2f(u0.w) * w0;
            a0 += bf2f(u1.x) * w1; a1 += bf2f(u1.y) * w1;
            a2 += bf2f(u1.z) * w1; a3 += bf2f(u1.w) * w1;
            a0 += bf2f(u2.x) * w2; a1 += bf2f(u2.y) * w2;
            a2 += bf2f(u2.z) * w2; a3 += bf2f(u2.w) * w2;
            a0 += bf2f(u3.x) * w3; a1 += bf2f(u3.y) * w3;
            a2 += bf2f(u3.z) * w3; a3 += bf2f(u3.w) * w3;
        }
        for (; e < cnt; e++) {
            int s0 = __shfl(av, e, 32);
            ushort4 u0 = *(const ushort4*)(h_bf + (size_t)s0 * HC + c0);
            float2 p0 = *(const float2*)(arw + (size_t)s0 * 8 + hh * 2);
            float t0 = alv + p0.x; t0 = (t0 > 0.f) ? t0 : NEG_SLOPE * t0;
            float w0 = __expf(t0) * p0.y;
            a0 += bf2f(u0.x) * w0; a1 += bf2f(u0.y) * w0;
            a2 += bf2f(u0.z) * w0; a3 += bf2f(u0.w) * w0;
        }
    }
    float4 b4 = *(const float4*)(bias + c0);
    *(float4*)(out + (size_t)n * HC + c0) =
        make_float4(a0 + b4.x, a1 + b4.y, a2 + b4.z, a3 + b4.w);
}

extern "C" void kernel_launch(void* const* d_in, const int* in_sizes, int n_in,
                              void* d_out, int out_size, void* d_ws, size_t ws_size,
                              hipStream_t stream) {
    const float* x    = (const float*)d_in[0];
    const float* W    = (const float*)d_in[1];
    const float* att  = (const float*)d_in[2];
    const float* bias = (const float*)d_in[3];
    const int*   ei   = (const int*)d_in[4];

    const int N  = in_sizes[0] / IND;     // 50000
    const int E  = in_sizes[4] / 2;       // 800000
    const int NE = E + N;
    const int ncb = (N + (1 << CSH) - 1) >> CSH;   // 196
    const int nsb = (NE + CHUNK - 1) / CHUNK;      // 208 scatter blocks
    const int ngb = (N + 127) / 128;               // 391 gemm blocks (256 thr)
    float* out = (float*)d_out;
    const int nodeTot = N * NH;
    const size_t capTot = (size_t)ncb * BCAP;      // 196*6144 ≈ 1.2M recs/side

    // ws layout
    unsigned short* h_bf  = (unsigned short*)d_ws;             // N*128 u16 = 12.8MB
    unsigned short* WT_bf = h_bf + (size_t)N * HC;             // 32K u16
    float* al   = (float*)(WT_bf + IND * HC);                  // N*4 f32
    float* ar   = al + nodeTot;                                // N*4
    float* arw  = ar + nodeTot;                                // N*8 = 1.6MB
    unsigned int* recS = (unsigned int*)(arw + (size_t)N * 8); // ncb*BCAP u32
    unsigned int* recD = recS + capTot;                        // ncb*BCAP u32
    unsigned short* adjD = (unsigned short*)(recD + capTot);   // ncb*BCAP u16
    int* rowB    = (int*)(adjD + capTot + (capTot & 1));       // N
    int* rowE    = rowB + N;                                   // N
    int* gcurS   = rowE + N;                                   // ncb
    int* gcurD   = gcurS + NCB_MAX;                            // ncb

    k_wprep<<<(IND * HC + 255) / 256, 256, 0, stream>>>(W, WT_bf, gcurS, gcurD);
    k_gs<<<nsb + ngb, 256, 0, stream>>>(x, WT_bf, att, h_bf, al, ar, ei,
                                        gcurS, gcurD, recS, recD,
                                        E, NE, ncb, nsb, N);
    k_bucket<<<2 * ncb, 256, 0, stream>>>(recS, recD, gcurS, gcurD, al, ar,
                                          adjD, rowB, rowE, arw, ncb, N);
    k_agg<<<(N + 7) / 8, 256, 0, stream>>>(rowB, rowE, adjD, al, arw, h_bf,
                                           bias, out, N);
}